// Round 2
// baseline (344.895 us; speedup 1.0000x reference)
//
#include <hip/hip_runtime.h>

namespace {

constexpr int Bn   = 16;
constexpr int Mn   = 128;
constexpr int NHn  = 256;
constexpr int EHn  = 128;
constexpr int ROWS = Bn * Mn;           // 2048
constexpr int HW   = 2 * NHn + EHn;     // 640  (h width: [agg_node | agg_edge | X])

__device__ __forceinline__ float4 f4zero() { return make_float4(0.f, 0.f, 0.f, 0.f); }

__device__ __forceinline__ void f4fma(float4& acc, float a, const float4& v) {
    acc.x = fmaf(a, v.x, acc.x);
    acc.y = fmaf(a, v.y, acc.y);
    acc.z = fmaf(a, v.z, acc.z);
    acc.w = fmaf(a, v.w, acc.w);
}

__device__ __forceinline__ float4 f4add(const float4& a, const float4& b) {
    return make_float4(a.x + b.x, a.y + b.y, a.z + b.z, a.w + b.w);
}

__device__ __forceinline__ float4 f4relu(const float4& a) {
    return make_float4(fmaxf(a.x, 0.f), fmaxf(a.y, 0.f),
                       fmaxf(a.z, 0.f), fmaxf(a.w, 0.f));
}

// ---------------------------------------------------------------------------
// Kernel 1: per (b,j) output row:
//   T[row][f]  = sum_i A[b,i,j] * E[b,i,j,f]        (f in [0,128))
//   AX[row][d] = sum_i A[b,i,j] * X[b,i,d]          (d in [0,256))
//   CS[row]    = sum_i A[b,i,j]
// The E stream (134 MB, read exactly once) is the HBM floor of the whole op.
// ---------------------------------------------------------------------------
__global__ __launch_bounds__(256) void k_reduce(
    const float* __restrict__ E, const float* __restrict__ A,
    const float* __restrict__ X,
    float* __restrict__ T, float* __restrict__ AX, float* __restrict__ CS)
{
    const int bid = blockIdx.x;           // row = b*128 + j
    const int b   = bid >> 7;
    const int j   = bid & (Mn - 1);
    const int tid = threadIdx.x;
    const int wv  = tid >> 6;             // wave id 0..3

    __shared__ float  acol[Mn];           // A[b,:,j] staged once
    __shared__ float4 tbuf[4][32];        // per-wave partial T
    __shared__ float  abuf[4];            // per-wave partial colsum
    __shared__ float4 axbuf[4][64];       // per-wave partial AX

    const float* Acol = A + (size_t)b * Mn * Mn + j;                     // [i*Mn]
    const float* Eb   = E + (size_t)b * Mn * Mn * EHn + (size_t)j * EHn; // + i*Mn*EHn + f

    // stage the stride-512B A column into LDS once
    if (tid < Mn) acol[tid] = Acol[(size_t)tid * Mn];
    __syncthreads();

    // ---- T + colsum: 8 i-groups x 32 float4 lanes ----
    {
        const int g  = tid >> 5;          // i-group 0..7
        const int f4 = tid & 31;          // float4 index into 128 floats
        float4 acc = f4zero();
        float  as  = 0.f;
        #pragma unroll
        for (int it = 0; it < 16; ++it) {
            const int   i  = it * 8 + g;
            const float a  = acol[i];
            const float4 e4 = *reinterpret_cast<const float4*>(
                Eb + (size_t)i * (Mn * EHn) + f4 * 4);
            f4fma(acc, a, e4);
            as += a;
        }
        // combine the two i-groups within each wave (lanes L <-> L^32 share f4)
        acc.x += __shfl_xor(acc.x, 32);
        acc.y += __shfl_xor(acc.y, 32);
        acc.z += __shfl_xor(acc.z, 32);
        acc.w += __shfl_xor(acc.w, 32);
        as    += __shfl_xor(as, 32);
        if ((tid & 63) < 32) tbuf[wv][f4] = acc;
        if ((tid & 63) == 0) abuf[wv] = as;
    }

    // ---- AX: 4 i-groups (= waves) x 64 float4 lanes ----
    {
        const int d4 = tid & 63;
        float4 ax = f4zero();
        #pragma unroll 4
        for (int it = 0; it < 32; ++it) {
            const int   i = it * 4 + wv;
            const float a = acol[i];
            const float4 x4 = *reinterpret_cast<const float4*>(
                X + (size_t)(b * Mn + i) * NHn + d4 * 4);
            f4fma(ax, a, x4);
        }
        axbuf[wv][d4] = ax;
    }
    __syncthreads();

    if (tid < 32) {
        float4 s = f4add(f4add(tbuf[0][tid], tbuf[1][tid]),
                         f4add(tbuf[2][tid], tbuf[3][tid]));
        *reinterpret_cast<float4*>(T + (size_t)bid * EHn + tid * 4) = s;
    }
    if (tid == 0) {
        CS[bid] = abuf[0] + abuf[1] + abuf[2] + abuf[3];
    }
    if (tid < 64) {
        float4 s = f4add(f4add(axbuf[0][tid], axbuf[1][tid]),
                         f4add(axbuf[2][tid], axbuf[3][tid]));
        *reinterpret_cast<float4*>(AX + (size_t)bid * NHn + tid * 4) = s;
    }
}

// ---------------------------------------------------------------------------
// Kernel 2: build H[row][640] = [ relu(AX@Wv + CS*Wvb) | relu(T@We + CS*Web) | relu(X) ]
// 8 rows per block; weights are L2-resident, loaded as coalesced float4;
// per-row operands are wave-uniform -> broadcast loads.
// ---------------------------------------------------------------------------
__global__ __launch_bounds__(256) void k_premix(
    const float* __restrict__ AX, const float* __restrict__ T,
    const float* __restrict__ CS, const float* __restrict__ X,
    const float* __restrict__ Wv, const float* __restrict__ Wvb,
    const float* __restrict__ We, const float* __restrict__ Web,
    float* __restrict__ H)
{
    const int r0  = blockIdx.x * 8;
    const int tid = threadIdx.x;

    // ---- agg_node -> H[:, 0:256): 4 row-pairs x 64 float4 cols ----
    {
        const int gq = tid >> 6;          // 0..3 (wave id -> row pair)
        const int c  = tid & 63;          // float4 column
        const int ra = r0 + 2 * gq;
        const int rb = ra + 1;
        const float* pa = AX + (size_t)ra * NHn;
        const float* pb = AX + (size_t)rb * NHn;
        float4 a0 = f4zero(), a1 = f4zero();
        #pragma unroll 4
        for (int k = 0; k < NHn; ++k) {
            const float4 wv4 = *reinterpret_cast<const float4*>(
                Wv + (size_t)k * NHn + c * 4);
            f4fma(a0, pa[k], wv4);
            f4fma(a1, pb[k], wv4);
        }
        const float4 wb = *reinterpret_cast<const float4*>(Wvb + c * 4);
        f4fma(a0, CS[ra], wb);
        f4fma(a1, CS[rb], wb);
        *reinterpret_cast<float4*>(H + (size_t)ra * HW + c * 4) = f4relu(a0);
        *reinterpret_cast<float4*>(H + (size_t)rb * HW + c * 4) = f4relu(a1);
    }

    // ---- agg_edge -> H[:, 256:384): 8 rows x 32 float4 cols ----
    {
        const int gq = tid >> 5;          // 0..7 -> row
        const int c  = tid & 31;
        const int r  = r0 + gq;
        const float* pt = T + (size_t)r * EHn;
        float4 a = f4zero();
        #pragma unroll 4
        for (int k = 0; k < EHn; ++k) {
            const float4 we4 = *reinterpret_cast<const float4*>(
                We + (size_t)k * EHn + c * 4);
            f4fma(a, pt[k], we4);
        }
        const float4 wb = *reinterpret_cast<const float4*>(Web + c * 4);
        f4fma(a, CS[r], wb);
        *reinterpret_cast<float4*>(H + (size_t)r * HW + NHn + c * 4) = f4relu(a);
    }

    // ---- relu(X) -> H[:, 384:640): 8 rows x 64 float4 cols ----
    #pragma unroll
    for (int idx = tid; idx < 8 * 64; idx += 256) {
        const int r = idx >> 6;
        const int c = idx & 63;
        const float4 x4 = *reinterpret_cast<const float4*>(
            X + (size_t)(r0 + r) * NHn + c * 4);
        *reinterpret_cast<float4*>(
            H + (size_t)(r0 + r) * HW + (NHn + EHn) + c * 4) = f4relu(x4);
    }
}

// ---------------------------------------------------------------------------
// Kernel 3: out[row][n] = (H[row,:] @ Wu + Wub)[n] * w[row]
// 8 rows/block, thread = (row pair, 4 cols): 8 fp32 acc, K=640.
// ---------------------------------------------------------------------------
__global__ __launch_bounds__(256) void k_final(
    const float* __restrict__ H, const float* __restrict__ Wu,
    const float* __restrict__ Wub, const float* __restrict__ wrow,
    float* __restrict__ out)
{
    const int r0  = blockIdx.x * 8;
    const int tid = threadIdx.x;
    const int gq  = tid >> 6;             // 0..3 -> row pair
    const int c   = tid & 63;             // float4 column
    const int ra  = r0 + 2 * gq;
    const int rb  = ra + 1;
    const float* pa = H + (size_t)ra * HW;
    const float* pb = H + (size_t)rb * HW;
    float4 a0 = f4zero(), a1 = f4zero();
    #pragma unroll 4
    for (int k = 0; k < HW; ++k) {
        const float4 wu4 = *reinterpret_cast<const float4*>(
            Wu + (size_t)k * NHn + c * 4);
        f4fma(a0, pa[k], wu4);
        f4fma(a1, pb[k], wu4);
    }
    const float4 wb = *reinterpret_cast<const float4*>(Wub + c * 4);
    const float w0 = wrow[ra], w1 = wrow[rb];
    float4 o0, o1;
    o0.x = (a0.x + wb.x) * w0;  o0.y = (a0.y + wb.y) * w0;
    o0.z = (a0.z + wb.z) * w0;  o0.w = (a0.w + wb.w) * w0;
    o1.x = (a1.x + wb.x) * w1;  o1.y = (a1.y + wb.y) * w1;
    o1.z = (a1.z + wb.z) * w1;  o1.w = (a1.w + wb.w) * w1;
    *reinterpret_cast<float4*>(out + (size_t)ra * NHn + c * 4) = o0;
    *reinterpret_cast<float4*>(out + (size_t)rb * NHn + c * 4) = o1;
}

} // anonymous namespace

extern "C" void kernel_launch(void* const* d_in, const int* in_sizes, int n_in,
                              void* d_out, int out_size, void* d_ws, size_t ws_size,
                              hipStream_t stream) {
    const float* X   = (const float*)d_in[0];   // [16,128,256]
    const float* E   = (const float*)d_in[1];   // [16,128,128,128]
    const float* A   = (const float*)d_in[2];   // [16,128,128]
    const float* w   = (const float*)d_in[3];   // [16,128,1]
    const float* Wv  = (const float*)d_in[4];   // [256,256]
    const float* Wvb = (const float*)d_in[5];   // [256]
    const float* We  = (const float*)d_in[6];   // [128,128]
    const float* Web = (const float*)d_in[7];   // [128]
    const float* Wu  = (const float*)d_in[8];   // [640,256]
    const float* Wub = (const float*)d_in[9];   // [256]
    float* out = (float*)d_out;                 // [16,128,256]

    float* ws = (float*)d_ws;
    float* T  = ws;                              // 2048*128
    float* AX = T  + (size_t)ROWS * EHn;         // 2048*256
    float* CS = AX + (size_t)ROWS * NHn;         // 2048
    float* H  = CS + ROWS;                       // 2048*640

    k_reduce<<<ROWS, 256, 0, stream>>>(E, A, X, T, AX, CS);
    k_premix<<<ROWS / 8, 256, 0, stream>>>(AX, T, CS, X, Wv, Wvb, We, Web, H);
    k_final<<<ROWS / 8, 256, 0, stream>>>(H, Wu, Wub, w, out);
}

// Round 3
// 297.866 us; speedup vs baseline: 1.1579x; 1.1579x over previous
//
#include <hip/hip_runtime.h>

namespace {

constexpr int Bn   = 16;
constexpr int Mn   = 128;
constexpr int NHn  = 256;
constexpr int EHn  = 128;
constexpr int ROWS = Bn * Mn;           // 2048
constexpr int HW   = 2 * NHn + EHn;     // 640

__device__ __forceinline__ float4 f4zero() { return make_float4(0.f, 0.f, 0.f, 0.f); }

__device__ __forceinline__ void f4fma(float4& acc, float a, const float4& v) {
    acc.x = fmaf(a, v.x, acc.x);
    acc.y = fmaf(a, v.y, acc.y);
    acc.z = fmaf(a, v.z, acc.z);
    acc.w = fmaf(a, v.w, acc.w);
}

__device__ __forceinline__ float4 f4add(const float4& a, const float4& b) {
    return make_float4(a.x + b.x, a.y + b.y, a.z + b.z, a.w + b.w);
}

__device__ __forceinline__ float4 f4relu(const float4& a) {
    return make_float4(fmaxf(a.x, 0.f), fmaxf(a.y, 0.f),
                       fmaxf(a.z, 0.f), fmaxf(a.w, 0.f));
}

// ---------------------------------------------------------------------------
// Kernel 0: N = X @ Wv + bv   [2048 x 256], K=256.
// 16-row x 128-col tiles, X tile staged in LDS, thread = 2 rows x 1 float4.
// ---------------------------------------------------------------------------
__global__ __launch_bounds__(256) void k_nodemap(
    const float* __restrict__ X, const float* __restrict__ Wv,
    const float* __restrict__ Wvb, float* __restrict__ N)
{
    const int bid  = blockIdx.x;
    const int r0   = (bid >> 1) * 16;
    const int half = bid & 1;             // col half: cols [half*128, half*128+128)
    const int tid  = threadIdx.x;

    __shared__ float xs[16][256];

    #pragma unroll
    for (int p = 0; p < 4; ++p) {
        const int idx = p * 256 + tid;
        const int r = idx >> 6, c = idx & 63;
        *reinterpret_cast<float4*>(&xs[r][c * 4]) =
            *reinterpret_cast<const float4*>(X + (size_t)(r0 + r) * NHn + c * 4);
    }
    __syncthreads();

    const int r2 = tid >> 5;              // 0..7 -> row pair
    const int c  = tid & 31;              // f4 col within half
    const int ra = 2 * r2, rb = ra + 1;
    const float* xa = xs[ra];
    const float* xb = xs[rb];
    const float* Wcol = Wv + half * 128 + c * 4;

    float4 a0 = f4zero(), a1 = f4zero();
    #pragma unroll 8
    for (int k = 0; k < NHn; ++k) {
        const float4 wv4 = *reinterpret_cast<const float4*>(Wcol + (size_t)k * NHn);
        f4fma(a0, xa[k], wv4);
        f4fma(a1, xb[k], wv4);
    }
    const float4 bv = *reinterpret_cast<const float4*>(Wvb + half * 128 + c * 4);
    a0 = f4add(a0, bv);
    a1 = f4add(a1, bv);
    *reinterpret_cast<float4*>(N + (size_t)(r0 + ra) * NHn + half * 128 + c * 4) = a0;
    *reinterpret_cast<float4*>(N + (size_t)(r0 + rb) * NHn + half * 128 + c * 4) = a1;
}

// ---------------------------------------------------------------------------
// Kernel 1: per (b,j) output row:
//   T[row][f]  = sum_i A[b,i,j] * E[b,i,j,f]   (the 134 MB HBM stream = floor)
//   AN[row][d] = sum_i A[b,i,j] * N[b,i,d]     (N is L2-resident, 2 MB)
//   CS[row]    = sum_i A[b,i,j]
// ---------------------------------------------------------------------------
__global__ __launch_bounds__(256) void k_reduce(
    const float* __restrict__ E, const float* __restrict__ A,
    const float* __restrict__ NM,
    float* __restrict__ T, float* __restrict__ AN, float* __restrict__ CS)
{
    const int bid = blockIdx.x;           // row = b*128 + j
    const int b   = bid >> 7;
    const int j   = bid & (Mn - 1);
    const int tid = threadIdx.x;
    const int wv  = tid >> 6;             // wave id 0..3

    __shared__ float  acol[Mn];
    __shared__ float4 tbuf[4][32];
    __shared__ float  abuf[4];
    __shared__ float4 axbuf[4][64];

    const float* Acol = A + (size_t)b * Mn * Mn + j;
    const float* Eb   = E + (size_t)b * Mn * Mn * EHn + (size_t)j * EHn;

    if (tid < Mn) acol[tid] = Acol[(size_t)tid * Mn];
    __syncthreads();

    // ---- T + colsum: 8 i-groups x 32 float4 lanes ----
    {
        const int g  = tid >> 5;
        const int f4 = tid & 31;
        float4 acc = f4zero();
        float  as  = 0.f;
        #pragma unroll
        for (int it = 0; it < 16; ++it) {
            const int   i = it * 8 + g;
            const float a = acol[i];
            const float4 e4 = *reinterpret_cast<const float4*>(
                Eb + (size_t)i * (Mn * EHn) + f4 * 4);
            f4fma(acc, a, e4);
            as += a;
        }
        acc.x += __shfl_xor(acc.x, 32);
        acc.y += __shfl_xor(acc.y, 32);
        acc.z += __shfl_xor(acc.z, 32);
        acc.w += __shfl_xor(acc.w, 32);
        as    += __shfl_xor(as, 32);
        if ((tid & 63) < 32) tbuf[wv][f4] = acc;
        if ((tid & 63) == 0) abuf[wv] = as;
    }

    // ---- AN: 4 i-groups (= waves) x 64 float4 lanes ----
    {
        const int d4 = tid & 63;
        float4 ax = f4zero();
        #pragma unroll 4
        for (int it = 0; it < 32; ++it) {
            const int   i = it * 4 + wv;
            const float a = acol[i];
            const float4 n4 = *reinterpret_cast<const float4*>(
                NM + (size_t)(b * Mn + i) * NHn + d4 * 4);
            f4fma(ax, a, n4);
        }
        axbuf[wv][d4] = ax;
    }
    __syncthreads();

    if (tid < 32) {
        float4 s = f4add(f4add(tbuf[0][tid], tbuf[1][tid]),
                         f4add(tbuf[2][tid], tbuf[3][tid]));
        *reinterpret_cast<float4*>(T + (size_t)bid * EHn + tid * 4) = s;
    }
    if (tid == 0) {
        CS[bid] = abuf[0] + abuf[1] + abuf[2] + abuf[3];
    }
    if (tid < 64) {
        float4 s = f4add(f4add(axbuf[0][tid], axbuf[1][tid]),
                         f4add(axbuf[2][tid], axbuf[3][tid]));
        *reinterpret_cast<float4*>(AN + (size_t)bid * NHn + tid * 4) = s;
    }
}

// ---------------------------------------------------------------------------
// Kernel 2 (fused): per 16-row x 128-col tile:
//   h = [ relu(AN) | relu(T@We + CS*be) | relu(X) ]   (in LDS, 40 KB)
//   out = (h @ Wu[:, half] + bu) * w
// 256 blocks x 256 threads; weights stream coalesced from L2; h from LDS
// broadcast (2-way alias = free); 2 indep f4 acc chains/thread, unroll 8.
// ---------------------------------------------------------------------------
__global__ __launch_bounds__(256) void k_mix(
    const float* __restrict__ AN, const float* __restrict__ T,
    const float* __restrict__ CS, const float* __restrict__ X,
    const float* __restrict__ We, const float* __restrict__ Web,
    const float* __restrict__ Wu, const float* __restrict__ Wub,
    const float* __restrict__ wrow, float* __restrict__ out)
{
    const int bid  = blockIdx.x;
    const int r0   = (bid >> 1) * 16;
    const int half = bid & 1;
    const int tid  = threadIdx.x;

    __shared__ float hs[16][HW];          // 40 KB
    __shared__ float tb[16][132];         // padded: banks r*132+k -> conflict-free
    __shared__ float csb[16];

    // stage relu(AN) -> hs[:, 0:256)
    #pragma unroll
    for (int p = 0; p < 4; ++p) {
        const int idx = p * 256 + tid;
        const int r = idx >> 6, c = idx & 63;
        const float4 v = *reinterpret_cast<const float4*>(
            AN + (size_t)(r0 + r) * NHn + c * 4);
        *reinterpret_cast<float4*>(&hs[r][c * 4]) = f4relu(v);
    }
    // stage relu(X) -> hs[:, 384:640)
    #pragma unroll
    for (int p = 0; p < 4; ++p) {
        const int idx = p * 256 + tid;
        const int r = idx >> 6, c = idx & 63;
        const float4 v = *reinterpret_cast<const float4*>(
            X + (size_t)(r0 + r) * NHn + c * 4);
        *reinterpret_cast<float4*>(&hs[r][NHn + EHn + c * 4]) = f4relu(v);
    }
    // stage T raw
    #pragma unroll
    for (int p = 0; p < 2; ++p) {
        const int idx = p * 256 + tid;
        const int r = idx >> 5, c = idx & 31;
        *reinterpret_cast<float4*>(&tb[r][c * 4]) =
            *reinterpret_cast<const float4*>(T + (size_t)(r0 + r) * EHn + c * 4);
    }
    if (tid < 16) csb[tid] = CS[r0 + tid];
    __syncthreads();

    // edge GEMM: hs[:, 256:384) = relu(T @ We + CS*be); thread = 1 row x 2 f4
    {
        const int r  = tid >> 4;          // 0..15
        const int ec = tid & 15;          // f4 col; also handles ec+16
        const float* tr = tb[r];
        float4 e0 = f4zero(), e1 = f4zero();
        #pragma unroll 4
        for (int k = 0; k < EHn; ++k) {
            const float a = tr[k];
            const float4 w0 = *reinterpret_cast<const float4*>(
                We + (size_t)k * EHn + ec * 4);
            const float4 w1 = *reinterpret_cast<const float4*>(
                We + (size_t)k * EHn + (ec + 16) * 4);
            f4fma(e0, a, w0);
            f4fma(e1, a, w1);
        }
        const float cs = csb[r];
        const float4 b0 = *reinterpret_cast<const float4*>(Web + ec * 4);
        const float4 b1 = *reinterpret_cast<const float4*>(Web + (ec + 16) * 4);
        f4fma(e0, cs, b0);
        f4fma(e1, cs, b1);
        *reinterpret_cast<float4*>(&hs[r][NHn + ec * 4]) = f4relu(e0);
        *reinterpret_cast<float4*>(&hs[r][NHn + (ec + 16) * 4]) = f4relu(e1);
    }
    __syncthreads();

    // layer 2: out tile = (hs @ Wu[:, half*128 + ...] + bu) * w
    const int r2 = tid >> 5;              // 0..7 -> row pair
    const int c  = tid & 31;              // f4 col within half
    const int ra = 2 * r2, rb = ra + 1;
    const float* ha = hs[ra];
    const float* hb = hs[rb];
    const float* Wcol = Wu + half * 128 + c * 4;

    float4 a0 = f4zero(), a1 = f4zero();
    #pragma unroll 8
    for (int k = 0; k < HW; ++k) {
        const float4 wu4 = *reinterpret_cast<const float4*>(Wcol + (size_t)k * NHn);
        f4fma(a0, ha[k], wu4);
        f4fma(a1, hb[k], wu4);
    }
    const float4 bu = *reinterpret_cast<const float4*>(Wub + half * 128 + c * 4);
    const float w0 = wrow[r0 + ra], w1 = wrow[r0 + rb];
    float4 o0, o1;
    o0.x = (a0.x + bu.x) * w0;  o0.y = (a0.y + bu.y) * w0;
    o0.z = (a0.z + bu.z) * w0;  o0.w = (a0.w + bu.w) * w0;
    o1.x = (a1.x + bu.x) * w1;  o1.y = (a1.y + bu.y) * w1;
    o1.z = (a1.z + bu.z) * w1;  o1.w = (a1.w + bu.w) * w1;
    *reinterpret_cast<float4*>(out + (size_t)(r0 + ra) * NHn + half * 128 + c * 4) = o0;
    *reinterpret_cast<float4*>(out + (size_t)(r0 + rb) * NHn + half * 128 + c * 4) = o1;
}

} // anonymous namespace

extern "C" void kernel_launch(void* const* d_in, const int* in_sizes, int n_in,
                              void* d_out, int out_size, void* d_ws, size_t ws_size,
                              hipStream_t stream) {
    const float* X   = (const float*)d_in[0];   // [16,128,256]
    const float* E   = (const float*)d_in[1];   // [16,128,128,128]
    const float* A   = (const float*)d_in[2];   // [16,128,128]
    const float* w   = (const float*)d_in[3];   // [16,128,1]
    const float* Wv  = (const float*)d_in[4];   // [256,256]
    const float* Wvb = (const float*)d_in[5];   // [256]
    const float* We  = (const float*)d_in[6];   // [128,128]
    const float* Web = (const float*)d_in[7];   // [128]
    const float* Wu  = (const float*)d_in[8];   // [640,256]
    const float* Wub = (const float*)d_in[9];   // [256]
    float* out = (float*)d_out;                 // [16,128,256]

    float* ws  = (float*)d_ws;
    float* Nb  = ws;                             // 2048*256
    float* T   = Nb + (size_t)ROWS * NHn;        // 2048*128
    float* AN  = T  + (size_t)ROWS * EHn;        // 2048*256
    float* CS  = AN + (size_t)ROWS * NHn;        // 2048

    k_nodemap<<<ROWS / 16 * 2, 256, 0, stream>>>(X, Wv, Wvb, Nb);
    k_reduce<<<ROWS, 256, 0, stream>>>(E, A, Nb, T, AN, CS);
    k_mix<<<ROWS / 16 * 2, 256, 0, stream>>>(AN, T, CS, X, We, Web, Wu, Wub, w, out);
}

// Round 4
// 291.413 us; speedup vs baseline: 1.1835x; 1.0221x over previous
//
#include <hip/hip_runtime.h>

namespace {

constexpr int Bn   = 16;
constexpr int Mn   = 128;
constexpr int NHn  = 256;
constexpr int EHn  = 128;
constexpr int ROWS = Bn * Mn;           // 2048
constexpr int HW   = 2 * NHn + EHn;     // 640

__device__ __forceinline__ float4 f4zero() { return make_float4(0.f, 0.f, 0.f, 0.f); }

__device__ __forceinline__ void f4fma(float4& acc, float a, const float4& v) {
    acc.x = fmaf(a, v.x, acc.x);
    acc.y = fmaf(a, v.y, acc.y);
    acc.z = fmaf(a, v.z, acc.z);
    acc.w = fmaf(a, v.w, acc.w);
}

__device__ __forceinline__ float4 f4add(const float4& a, const float4& b) {
    return make_float4(a.x + b.x, a.y + b.y, a.z + b.z, a.w + b.w);
}

__device__ __forceinline__ float4 f4relu(const float4& a) {
    return make_float4(fmaxf(a.x, 0.f), fmaxf(a.y, 0.f),
                       fmaxf(a.z, 0.f), fmaxf(a.w, 0.f));
}

// ---------------------------------------------------------------------------
// Kernel 1: per (b,j) output row:
//   T[row][f]  = sum_i A[b,i,j] * E[b,i,j,f]   (134 MB E stream = HBM floor)
//   AX[row][d] = sum_i A[b,i,j] * X[b,i,d]     (X is L2-resident, 2 MB)
//   CS[row]    = sum_i A[b,i,j]
// 2048 blocks x 256 thr = 8 blocks/CU, 32 waves/CU (max occupancy).
// ---------------------------------------------------------------------------
__global__ __launch_bounds__(256) void k_reduce(
    const float* __restrict__ E, const float* __restrict__ A,
    const float* __restrict__ X,
    float* __restrict__ T, float* __restrict__ AX, float* __restrict__ CS)
{
    const int bid = blockIdx.x;           // row = b*128 + j
    const int b   = bid >> 7;
    const int j   = bid & (Mn - 1);
    const int tid = threadIdx.x;
    const int wv  = tid >> 6;             // wave id 0..3

    __shared__ float  acol[Mn];
    __shared__ float4 tbuf[4][32];
    __shared__ float  abuf[4];
    __shared__ float4 axbuf[4][64];

    const float* Acol = A + (size_t)b * Mn * Mn + j;
    const float* Eb   = E + (size_t)b * Mn * Mn * EHn + (size_t)j * EHn;

    if (tid < Mn) acol[tid] = Acol[(size_t)tid * Mn];
    __syncthreads();

    // ---- T + colsum: 8 i-groups x 32 float4 lanes ----
    {
        const int g  = tid >> 5;
        const int f4 = tid & 31;
        float4 acc = f4zero();
        float  as  = 0.f;
        #pragma unroll
        for (int it = 0; it < 16; ++it) {
            const int   i = it * 8 + g;
            const float a = acol[i];
            const float4 e4 = *reinterpret_cast<const float4*>(
                Eb + (size_t)i * (Mn * EHn) + f4 * 4);
            f4fma(acc, a, e4);
            as += a;
        }
        acc.x += __shfl_xor(acc.x, 32);
        acc.y += __shfl_xor(acc.y, 32);
        acc.z += __shfl_xor(acc.z, 32);
        acc.w += __shfl_xor(acc.w, 32);
        as    += __shfl_xor(as, 32);
        if ((tid & 63) < 32) tbuf[wv][f4] = acc;
        if ((tid & 63) == 0) abuf[wv] = as;
    }

    // ---- AX: 4 i-groups (= waves) x 64 float4 lanes ----
    {
        const int d4 = tid & 63;
        float4 ax = f4zero();
        #pragma unroll 4
        for (int it = 0; it < 32; ++it) {
            const int   i = it * 4 + wv;
            const float a = acol[i];
            const float4 x4 = *reinterpret_cast<const float4*>(
                X + (size_t)(b * Mn + i) * NHn + d4 * 4);
            f4fma(ax, a, x4);
        }
        axbuf[wv][d4] = ax;
    }
    __syncthreads();

    if (tid < 32) {
        float4 s = f4add(f4add(tbuf[0][tid], tbuf[1][tid]),
                         f4add(tbuf[2][tid], tbuf[3][tid]));
        *reinterpret_cast<float4*>(T + (size_t)bid * EHn + tid * 4) = s;
    }
    if (tid == 0) {
        CS[bid] = abuf[0] + abuf[1] + abuf[2] + abuf[3];
    }
    if (tid < 64) {
        float4 s = f4add(f4add(axbuf[0][tid], axbuf[1][tid]),
                         f4add(axbuf[2][tid], axbuf[3][tid]));
        *reinterpret_cast<float4*>(AX + (size_t)bid * NHn + tid * 4) = s;
    }
}

// ---------------------------------------------------------------------------
// Kernel 2 (fused): per 8-row tile (256 blocks x 512 threads, 2 waves/SIMD):
//   h = [ relu(AX@Wv + CS*bv) | relu(T@We + CS*be) | relu(X) ]  (hs in LDS)
//   out = (h @ Wu + bu) * w          (full 256 cols; Wu read once per block)
// Wave w owns row w: LDS operand reads are wave-uniform broadcasts (free);
// weight reads are 1 KB/wave coalesced f4 streams shared by all 8 waves.
// ---------------------------------------------------------------------------
__global__ __launch_bounds__(512) void k_mix(
    const float* __restrict__ AX, const float* __restrict__ T,
    const float* __restrict__ CS, const float* __restrict__ X,
    const float* __restrict__ Wv, const float* __restrict__ Wvb,
    const float* __restrict__ We, const float* __restrict__ Web,
    const float* __restrict__ Wu, const float* __restrict__ Wub,
    const float* __restrict__ wrow, float* __restrict__ out)
{
    const int r0  = blockIdx.x * 8;
    const int tid = threadIdx.x;
    const int r   = tid >> 6;             // 0..7 == wave id == row
    const int c   = tid & 63;             // f4 column (of 64)

    __shared__ float axs[8][NHn];         // 8 KB
    __shared__ float ts[8][EHn + 4];      // padded, 4.1 KB
    __shared__ float hs[8][HW];           // 20 KB
    __shared__ float csb[8];

    // stage AX tile (1 f4/thread)
    *reinterpret_cast<float4*>(&axs[r][c * 4]) =
        *reinterpret_cast<const float4*>(AX + (size_t)(r0 + r) * NHn + c * 4);
    // stage T tile (tid<256: 1 f4)
    if (tid < 256) {
        const int tr = tid >> 5, tc = tid & 31;
        *reinterpret_cast<float4*>(&ts[tr][tc * 4]) =
            *reinterpret_cast<const float4*>(T + (size_t)(r0 + tr) * EHn + tc * 4);
    }
    // stage relu(X) -> hs[:, 384:640)
    {
        const float4 x4 = *reinterpret_cast<const float4*>(
            X + (size_t)(r0 + r) * NHn + c * 4);
        *reinterpret_cast<float4*>(&hs[r][NHn + EHn + c * 4]) = f4relu(x4);
    }
    if (tid < 8) csb[tid] = CS[r0 + tid];
    __syncthreads();

    // ---- node pre-GEMM: hs[:, 0:256) = relu(AX @ Wv + CS*bv) ----
    {
        float4 acc = f4zero();
        const float* ax = axs[r];
        #pragma unroll 8
        for (int k = 0; k < NHn; ++k) {
            const float4 w4 = *reinterpret_cast<const float4*>(
                Wv + (size_t)k * NHn + c * 4);
            f4fma(acc, ax[k], w4);
        }
        const float4 bv = *reinterpret_cast<const float4*>(Wvb + c * 4);
        f4fma(acc, csb[r], bv);
        *reinterpret_cast<float4*>(&hs[r][c * 4]) = f4relu(acc);
    }
    // ---- edge pre-GEMM: hs[:, 256:384) = relu(T @ We + CS*be) ----
    if (tid < 256) {
        const int er = tid >> 5, ec = tid & 31;
        float4 acc = f4zero();
        const float* tr = ts[er];
        #pragma unroll 8
        for (int k = 0; k < EHn; ++k) {
            const float4 w4 = *reinterpret_cast<const float4*>(
                We + (size_t)k * EHn + ec * 4);
            f4fma(acc, tr[k], w4);
        }
        const float4 be = *reinterpret_cast<const float4*>(Web + ec * 4);
        f4fma(acc, csb[er], be);
        *reinterpret_cast<float4*>(&hs[er][NHn + ec * 4]) = f4relu(acc);
    }
    __syncthreads();

    // ---- layer 2: out[r0+r][:] = (hs[r] @ Wu + bu) * w ----
    {
        float4 acc = f4zero();
        const float* h = hs[r];
        #pragma unroll 8
        for (int k = 0; k < HW; ++k) {
            const float4 w4 = *reinterpret_cast<const float4*>(
                Wu + (size_t)k * NHn + c * 4);
            f4fma(acc, h[k], w4);
        }
        const float4 bu = *reinterpret_cast<const float4*>(Wub + c * 4);
        const float  ww = wrow[r0 + r];
        float4 o;
        o.x = (acc.x + bu.x) * ww;
        o.y = (acc.y + bu.y) * ww;
        o.z = (acc.z + bu.z) * ww;
        o.w = (acc.w + bu.w) * ww;
        *reinterpret_cast<float4*>(out + (size_t)(r0 + r) * NHn + c * 4) = o;
    }
}

} // anonymous namespace

extern "C" void kernel_launch(void* const* d_in, const int* in_sizes, int n_in,
                              void* d_out, int out_size, void* d_ws, size_t ws_size,
                              hipStream_t stream) {
    const float* X   = (const float*)d_in[0];   // [16,128,256]
    const float* E   = (const float*)d_in[1];   // [16,128,128,128]
    const float* A   = (const float*)d_in[2];   // [16,128,128]
    const float* w   = (const float*)d_in[3];   // [16,128,1]
    const float* Wv  = (const float*)d_in[4];   // [256,256]
    const float* Wvb = (const float*)d_in[5];   // [256]
    const float* We  = (const float*)d_in[6];   // [128,128]
    const float* Web = (const float*)d_in[7];   // [128]
    const float* Wu  = (const float*)d_in[8];   // [640,256]
    const float* Wub = (const float*)d_in[9];   // [256]
    float* out = (float*)d_out;                 // [16,128,256]

    float* ws = (float*)d_ws;
    float* T  = ws;                              // 2048*128
    float* AX = T  + (size_t)ROWS * EHn;         // 2048*256
    float* CS = AX + (size_t)ROWS * NHn;         // 2048

    k_reduce<<<ROWS, 256, 0, stream>>>(E, A, X, T, AX, CS);
    k_mix<<<ROWS / 8, 512, 0, stream>>>(AX, T, CS, X, Wv, Wvb, We, Web,
                                        Wu, Wub, w, out);
}

// Round 6
// 288.252 us; speedup vs baseline: 1.1965x; 1.0110x over previous
//
#include <hip/hip_runtime.h>

namespace {

constexpr int Bn   = 16;
constexpr int Mn   = 128;
constexpr int NHn  = 256;
constexpr int EHn  = 128;
constexpr int ROWS = Bn * Mn;           // 2048
constexpr int HW   = 2 * NHn + EHn;     // 640

// padded LDS row strides (floats); all are multiples of 4 -> 16-B aligned rows
constexpr int HP = HW + 4;              // 644
constexpr int AP = NHn + 4;             // 260
constexpr int TP = EHn + 4;             // 132

__device__ __forceinline__ float4 f4zero() { return make_float4(0.f, 0.f, 0.f, 0.f); }

__device__ __forceinline__ void f4fma(float4& acc, float a, const float4& v) {
    acc.x = fmaf(a, v.x, acc.x);
    acc.y = fmaf(a, v.y, acc.y);
    acc.z = fmaf(a, v.z, acc.z);
    acc.w = fmaf(a, v.w, acc.w);
}

__device__ __forceinline__ float4 f4add(const float4& a, const float4& b) {
    return make_float4(a.x + b.x, a.y + b.y, a.z + b.z, a.w + b.w);
}

__device__ __forceinline__ float4 f4relu(const float4& a) {
    return make_float4(fmaxf(a.x, 0.f), fmaxf(a.y, 0.f),
                       fmaxf(a.z, 0.f), fmaxf(a.w, 0.f));
}

// ---------------------------------------------------------------------------
// Kernel 1: per (b,j) output row:
//   T[row][f]  = sum_i A[b,i,j] * E[b,i,j,f]   (134 MB E stream = HBM floor)
//   AX[row][d] = sum_i A[b,i,j] * X[b,i,d]     (X is L2-resident, 2 MB)
//   CS[row]    = sum_i A[b,i,j]
// 2048 blocks x 256 thr = 8 blocks/CU, 32 waves/CU (max occupancy).
// ---------------------------------------------------------------------------
__global__ __launch_bounds__(256) void k_reduce(
    const float* __restrict__ E, const float* __restrict__ A,
    const float* __restrict__ X,
    float* __restrict__ T, float* __restrict__ AX, float* __restrict__ CS)
{
    const int bid = blockIdx.x;           // row = b*128 + j
    const int b   = bid >> 7;
    const int j   = bid & (Mn - 1);
    const int tid = threadIdx.x;
    const int wv  = tid >> 6;             // wave id 0..3

    __shared__ float  acol[Mn];
    __shared__ float4 tbuf[4][32];
    __shared__ float  abuf[4];
    __shared__ float4 axbuf[4][64];

    const float* Acol = A + (size_t)b * Mn * Mn + j;
    const float* Eb   = E + (size_t)b * Mn * Mn * EHn + (size_t)j * EHn;

    if (tid < Mn) acol[tid] = Acol[(size_t)tid * Mn];
    __syncthreads();

    // ---- T + colsum: 8 i-groups x 32 float4 lanes ----
    {
        const int g  = tid >> 5;
        const int f4 = tid & 31;
        float4 acc = f4zero();
        float  as  = 0.f;
        #pragma unroll
        for (int it = 0; it < 16; ++it) {
            const int   i = it * 8 + g;
            const float a = acol[i];
            const float4 e4 = *reinterpret_cast<const float4*>(
                Eb + (size_t)i * (Mn * EHn) + f4 * 4);
            f4fma(acc, a, e4);
            as += a;
        }
        acc.x += __shfl_xor(acc.x, 32);
        acc.y += __shfl_xor(acc.y, 32);
        acc.z += __shfl_xor(acc.z, 32);
        acc.w += __shfl_xor(acc.w, 32);
        as    += __shfl_xor(as, 32);
        if ((tid & 63) < 32) tbuf[wv][f4] = acc;
        if ((tid & 63) == 0) abuf[wv] = as;
    }

    // ---- AX: 4 i-groups (= waves) x 64 float4 lanes ----
    {
        const int d4 = tid & 63;
        float4 ax = f4zero();
        #pragma unroll 4
        for (int it = 0; it < 32; ++it) {
            const int   i = it * 4 + wv;
            const float a = acol[i];
            const float4 x4 = *reinterpret_cast<const float4*>(
                X + (size_t)(b * Mn + i) * NHn + d4 * 4);
            f4fma(ax, a, x4);
        }
        axbuf[wv][d4] = ax;
    }
    __syncthreads();

    if (tid < 32) {
        float4 s = f4add(f4add(tbuf[0][tid], tbuf[1][tid]),
                         f4add(tbuf[2][tid], tbuf[3][tid]));
        *reinterpret_cast<float4*>(T + (size_t)bid * EHn + tid * 4) = s;
    }
    if (tid == 0) {
        CS[bid] = abuf[0] + abuf[1] + abuf[2] + abuf[3];
    }
    if (tid < 64) {
        float4 s = f4add(f4add(axbuf[0][tid], axbuf[1][tid]),
                         f4add(axbuf[2][tid], axbuf[3][tid]));
        *reinterpret_cast<float4*>(AX + (size_t)bid * NHn + tid * 4) = s;
    }
}

// ---------------------------------------------------------------------------
// Kernel 2 (fused): 256 blocks x 256 thr, tile = 8 rows x 256 cols.
//   h = [ relu(AX@Wv + CS*bv) | relu(T@We + CS*be) | relu(X) ]  (hs in LDS)
//   out = (h @ Wu + bu) * w
// ILP structure: thread = 2 rows x 1 f4col; k stepped by 4 with one
// ds_read_b128 (wave-uniform broadcast) per row per step -> 32 FMAs per
// 2 b128 + 4 f4-weight loads. Weight streams are coalesced and L2-resident
// (Wu per XCD: 32 blocks x 640 KB = 20 MB @ ~4.3 TB/s/XCD ~= 5 us).
// ---------------------------------------------------------------------------
__global__ __launch_bounds__(256) void k_mix(
    const float* __restrict__ AX, const float* __restrict__ T,
    const float* __restrict__ CS, const float* __restrict__ X,
    const float* __restrict__ Wv, const float* __restrict__ Wvb,
    const float* __restrict__ We, const float* __restrict__ Web,
    const float* __restrict__ Wu, const float* __restrict__ Wub,
    const float* __restrict__ wrow, float* __restrict__ out)
{
    const int r0  = blockIdx.x * 8;
    const int tid = threadIdx.x;

    __shared__ float axs[8][AP];          // 8.3 KB
    __shared__ float ts[8][TP];           // 4.2 KB
    __shared__ float hs[8][HP];           // 20.6 KB
    __shared__ float csb[8];

    // ---- stage: AX (2 f4/thread), T (1 f4/thread), relu(X) (2 f4/thread) ----
    #pragma unroll
    for (int p = 0; p < 2; ++p) {
        const int idx = p * 256 + tid;
        const int r = idx >> 6, c = idx & 63;
        *reinterpret_cast<float4*>(&axs[r][c * 4]) =
            *reinterpret_cast<const float4*>(AX + (size_t)(r0 + r) * NHn + c * 4);
    }
    {
        const int r = tid >> 5, c = tid & 31;
        *reinterpret_cast<float4*>(&ts[r][c * 4]) =
            *reinterpret_cast<const float4*>(T + (size_t)(r0 + r) * EHn + c * 4);
    }
    #pragma unroll
    for (int p = 0; p < 2; ++p) {
        const int idx = p * 256 + tid;
        const int r = idx >> 6, c = idx & 63;
        const float4 x4 = *reinterpret_cast<const float4*>(
            X + (size_t)(r0 + r) * NHn + c * 4);
        *reinterpret_cast<float4*>(&hs[r][NHn + EHn + c * 4]) = f4relu(x4);
    }
    if (tid < 8) csb[tid] = CS[r0 + tid];
    __syncthreads();

    // ---- node pre-GEMM: hs[:, 0:256) = relu(AX @ Wv + CS*bv) ----
    {
        const int rg = tid >> 6;          // 0..3 -> rows 2rg, 2rg+1
        const int c4 = tid & 63;
        const int ra = 2 * rg, rb = ra + 1;
        float4 a0 = f4zero(), a1 = f4zero();
        #pragma unroll 2
        for (int k = 0; k < NHn; k += 4) {
            const float4 h4a = *reinterpret_cast<const float4*>(&axs[ra][k]);
            const float4 h4b = *reinterpret_cast<const float4*>(&axs[rb][k]);
            const float* wp = Wv + (size_t)k * NHn + c4 * 4;
            const float4 w0 = *reinterpret_cast<const float4*>(wp);
            const float4 w1 = *reinterpret_cast<const float4*>(wp + NHn);
            const float4 w2 = *reinterpret_cast<const float4*>(wp + 2 * NHn);
            const float4 w3 = *reinterpret_cast<const float4*>(wp + 3 * NHn);
            f4fma(a0, h4a.x, w0); f4fma(a1, h4b.x, w0);
            f4fma(a0, h4a.y, w1); f4fma(a1, h4b.y, w1);
            f4fma(a0, h4a.z, w2); f4fma(a1, h4b.z, w2);
            f4fma(a0, h4a.w, w3); f4fma(a1, h4b.w, w3);
        }
        const float4 bv = *reinterpret_cast<const float4*>(Wvb + c4 * 4);
        f4fma(a0, csb[ra], bv);
        f4fma(a1, csb[rb], bv);
        *reinterpret_cast<float4*>(&hs[ra][c4 * 4]) = f4relu(a0);
        *reinterpret_cast<float4*>(&hs[rb][c4 * 4]) = f4relu(a1);
    }
    // ---- edge pre-GEMM: hs[:, 256:384) = relu(T @ We + CS*be) ----
    {
        const int er = tid >> 5;          // 0..7 -> row
        const int ec = tid & 31;          // f4 col of 32
        float4 a = f4zero();
        #pragma unroll 2
        for (int k = 0; k < EHn; k += 4) {
            const float4 t4 = *reinterpret_cast<const float4*>(&ts[er][k]);
            const float* wp = We + (size_t)k * EHn + ec * 4;
            const float4 w0 = *reinterpret_cast<const float4*>(wp);
            const float4 w1 = *reinterpret_cast<const float4*>(wp + EHn);
            const float4 w2 = *reinterpret_cast<const float4*>(wp + 2 * EHn);
            const float4 w3 = *reinterpret_cast<const float4*>(wp + 3 * EHn);
            f4fma(a, t4.x, w0);
            f4fma(a, t4.y, w1);
            f4fma(a, t4.z, w2);
            f4fma(a, t4.w, w3);
        }
        const float4 be = *reinterpret_cast<const float4*>(Web + ec * 4);
        f4fma(a, csb[er], be);
        *reinterpret_cast<float4*>(&hs[er][NHn + ec * 4]) = f4relu(a);
    }
    __syncthreads();

    // ---- layer 2: out[r][:] = (hs[r] @ Wu + bu) * w, 2 rows/thread ----
    {
        const int rg = tid >> 6;          // 0..3 -> rows 2rg, 2rg+1
        const int c4 = tid & 63;
        const int ra = 2 * rg, rb = ra + 1;
        float4 a0 = f4zero(), a1 = f4zero();
        #pragma unroll 2
        for (int k = 0; k < HW; k += 4) {
            const float4 h4a = *reinterpret_cast<const float4*>(&hs[ra][k]);
            const float4 h4b = *reinterpret_cast<const float4*>(&hs[rb][k]);
            const float* wp = Wu + (size_t)k * NHn + c4 * 4;
            const float4 w0 = *reinterpret_cast<const float4*>(wp);
            const float4 w1 = *reinterpret_cast<const float4*>(wp + NHn);
            const float4 w2 = *reinterpret_cast<const float4*>(wp + 2 * NHn);
            const float4 w3 = *reinterpret_cast<const float4*>(wp + 3 * NHn);
            f4fma(a0, h4a.x, w0); f4fma(a1, h4b.x, w0);
            f4fma(a0, h4a.y, w1); f4fma(a1, h4b.y, w1);
            f4fma(a0, h4a.z, w2); f4fma(a1, h4b.z, w2);
            f4fma(a0, h4a.w, w3); f4fma(a1, h4b.w, w3);
        }
        const float4 bu = *reinterpret_cast<const float4*>(Wub + c4 * 4);
        const float w0 = wrow[r0 + ra], w1 = wrow[r0 + rb];
        float4 o0, o1;
        o0.x = (a0.x + bu.x) * w0;  o0.y = (a0.y + bu.y) * w0;
        o0.z = (a0.z + bu.z) * w0;  o0.w = (a0.w + bu.w) * w0;
        o1.x = (a1.x + bu.x) * w1;  o1.y = (a1.y + bu.y) * w1;
        o1.z = (a1.z + bu.z) * w1;  o1.w = (a1.w + bu.w) * w1;
        *reinterpret_cast<float4*>(out + (size_t)(r0 + ra) * NHn + c4 * 4) = o0;
        *reinterpret_cast<float4*>(out + (size_t)(r0 + rb) * NHn + c4 * 4) = o1;
    }
}

} // anonymous namespace

extern "C" void kernel_launch(void* const* d_in, const int* in_sizes, int n_in,
                              void* d_out, int out_size, void* d_ws, size_t ws_size,
                              hipStream_t stream) {
    const float* X   = (const float*)d_in[0];   // [16,128,256]
    const float* E   = (const float*)d_in[1];   // [16,128,128,128]
    const float* A   = (const float*)d_in[2];   // [16,128,128]
    const float* w   = (const float*)d_in[3];   // [16,128,1]
    const float* Wv  = (const float*)d_in[4];   // [256,256]
    const float* Wvb = (const float*)d_in[5];   // [256]
    const float* We  = (const float*)d_in[6];   // [128,128]
    const float* Web = (const float*)d_in[7];   // [128]
    const float* Wu  = (const float*)d_in[8];   // [640,256]
    const float* Wub = (const float*)d_in[9];   // [256]
    float* out = (float*)d_out;                 // [16,128,256]

    float* ws = (float*)d_ws;
    float* T  = ws;                              // 2048*128
    float* AX = T  + (size_t)ROWS * EHn;         // 2048*256
    float* CS = AX + (size_t)ROWS * NHn;         // 2048

    k_reduce<<<ROWS, 256, 0, stream>>>(E, A, X, T, AX, CS);
    k_mix<<<ROWS / 8, 256, 0, stream>>>(AX, T, CS, X, Wv, Wvb, We, Web,
                                        Wu, Wub, w, out);
}

// Round 7
// 260.295 us; speedup vs baseline: 1.3250x; 1.1074x over previous
//
#include <hip/hip_runtime.h>

namespace {

constexpr int Bn   = 16;
constexpr int Mn   = 128;
constexpr int NHn  = 256;
constexpr int EHn  = 128;
constexpr int ROWS = Bn * Mn;           // 2048
constexpr int HW   = 2 * NHn + EHn;     // 640

constexpr int HP = HW + 4;              // 644 (LDS strides, mult of 4)
constexpr int AP = NHn + 4;             // 260
constexpr int TP = EHn + 4;             // 132

__device__ __forceinline__ float4 f4zero() { return make_float4(0.f, 0.f, 0.f, 0.f); }
__device__ __forceinline__ float4 ld4(const float* p) {
    return *reinterpret_cast<const float4*>(p);
}
__device__ __forceinline__ void f4fma(float4& acc, float a, const float4& v) {
    acc.x = fmaf(a, v.x, acc.x);
    acc.y = fmaf(a, v.y, acc.y);
    acc.z = fmaf(a, v.z, acc.z);
    acc.w = fmaf(a, v.w, acc.w);
}
__device__ __forceinline__ float4 f4add(const float4& a, const float4& b) {
    return make_float4(a.x + b.x, a.y + b.y, a.z + b.z, a.w + b.w);
}
__device__ __forceinline__ float4 f4relu(const float4& a) {
    return make_float4(fmaxf(a.x, 0.f), fmaxf(a.y, 0.f),
                       fmaxf(a.z, 0.f), fmaxf(a.w, 0.f));
}

// load 4 consecutive weight rows (k..k+3) at column base wb (includes c4*4)
#define LOADW(B, wb, ldw, kk) {                                        \
    const float* _wp = (wb) + (size_t)(kk) * (ldw);                    \
    B[0] = ld4(_wp);                 B[1] = ld4(_wp + (ldw));          \
    B[2] = ld4(_wp + 2 * (ldw));     B[3] = ld4(_wp + 3 * (ldw)); }

// 2-row FMA vs weight buffer B at operand index kk
#define FMA2R(B, kk, opA, opB) {                                       \
    const float4 _ha = ld4(&(opA)[kk]);                                \
    const float4 _hb = ld4(&(opB)[kk]);                                \
    f4fma(a0, _ha.x, B[0]); f4fma(a1, _hb.x, B[0]);                    \
    f4fma(a0, _ha.y, B[1]); f4fma(a1, _hb.y, B[1]);                    \
    f4fma(a0, _ha.z, B[2]); f4fma(a1, _hb.z, B[2]);                    \
    f4fma(a0, _ha.w, B[3]); f4fma(a1, _hb.w, B[3]); }

// 1-row variant
#define FMA1R(B, kk, opA) {                                            \
    const float4 _ha = ld4(&(opA)[kk]);                                \
    f4fma(a0, _ha.x, B[0]); f4fma(a0, _ha.y, B[1]);                    \
    f4fma(a0, _ha.z, B[2]); f4fma(a0, _ha.w, B[3]); }

// ---------------------------------------------------------------------------
// Kernel 1: T[b,j,f] = sum_i A[b,i,j] * E[b,i,j,f]   (pure E stream)
// Block = (b, j-tile of 4): per i reads E[b,i,j0:j0+4,:] = 2 KB CONTIGUOUS
// (thread = (jj, float2 f)); each output cell owned by one thread -> no
// reduction. 512 blocks x 256 thr = 2 blocks/CU, 8 waves/CU.
// ---------------------------------------------------------------------------
__global__ __launch_bounds__(256) void k_reduce(
    const float* __restrict__ E, const float* __restrict__ A,
    float* __restrict__ T)
{
    const int bid = blockIdx.x;           // 512 = 16 b x 32 j-tiles
    const int b   = bid >> 5;
    const int j0  = (bid & 31) * 4;
    const int tid = threadIdx.x;

    __shared__ float acolT[4][Mn];        // A[b, :, j0+jj] transposed

    if (tid < Mn) {
        const float4 a4 = ld4(A + (size_t)b * Mn * Mn + (size_t)tid * Mn + j0);
        acolT[0][tid] = a4.x; acolT[1][tid] = a4.y;
        acolT[2][tid] = a4.z; acolT[3][tid] = a4.w;
    }
    __syncthreads();

    const int jj = tid >> 6;              // 0..3 (wave-uniform)
    const int f2 = tid & 63;              // float2 index into 128 floats
    const float* Eb = E + (size_t)b * Mn * Mn * EHn + (size_t)(j0 + jj) * EHn
                        + f2 * 2;
    const float* ac = acolT[jj];

    float2 acc = make_float2(0.f, 0.f);
    #pragma unroll 16
    for (int i = 0; i < Mn; ++i) {
        const float2 e2 = *reinterpret_cast<const float2*>(
            Eb + (size_t)i * (Mn * EHn));
        const float a = ac[i];            // LDS broadcast
        acc.x = fmaf(a, e2.x, acc.x);
        acc.y = fmaf(a, e2.y, acc.y);
    }

    const int row = b * Mn + j0 + jj;
    *reinterpret_cast<float2*>(T + (size_t)row * EHn + f2 * 2) = acc;
}

// ---------------------------------------------------------------------------
// Kernel 2 (fused, 256 blocks x 512 thr): per 8-row tile:
//   CS, AX (from A-slice + X) computed in-kernel;
//   h = [ relu(AX@Wv+CS*bv) | relu(T@We+CS*be) | relu(X) ]  in LDS
//   out = (h @ Wu + bu) * w
// Thread map for GEMM phases: (rg 0..3 -> 2 rows, c4 0..63, kh 0..1 = K/2
// split). Weights double-buffered 2x4 float4 in registers -> 8 loads in
// flight/wave x 2 waves/SIMD. Split-K halves dependent chains; combine via
// LDS. __launch_bounds__(512,2) gives VGPR headroom (<=128).
// ---------------------------------------------------------------------------
__global__ __launch_bounds__(512, 2) void k_mix(
    const float* __restrict__ T, const float* __restrict__ A,
    const float* __restrict__ X,
    const float* __restrict__ Wv, const float* __restrict__ Wvb,
    const float* __restrict__ We, const float* __restrict__ Web,
    const float* __restrict__ Wu, const float* __restrict__ Wub,
    const float* __restrict__ wrow, float* __restrict__ out)
{
    const int r0  = blockIdx.x * 8;       // global row tile (b, j0..j0+7)
    const int b   = r0 >> 7;
    const int j0  = r0 & 127;
    const int tid = threadIdx.x;

    __shared__ float  asl[Mn][8];         // A[b,i,j0+jj]        4 KB
    __shared__ float  ts[8][TP];          // T rows              4.2 KB
    __shared__ float  axs[8][AP];         // AX rows             8.3 KB
    __shared__ float  hs[8][HP];          // h rows              20.6 KB
    __shared__ float4 comb[256][2];       // split-K combine     8 KB
    __shared__ float  pcs[8][8];
    __shared__ float  csb[8];

    // ---- stage: A-slice, T, relu(X) ----
    {
        const int i = tid >> 2, q = tid & 3;
        const float2 a2 = *reinterpret_cast<const float2*>(
            A + (size_t)b * Mn * Mn + (size_t)i * Mn + j0 + q * 2);
        asl[i][q * 2]     = a2.x;
        asl[i][q * 2 + 1] = a2.y;
    }
    if (tid < 256) {
        const int r = tid >> 5, c = tid & 31;
        *reinterpret_cast<float4*>(&ts[r][c * 4]) =
            ld4(T + (size_t)(r0 + r) * EHn + c * 4);
    }
    {
        const int r = tid >> 6, c4 = tid & 63;
        const float4 x4 = ld4(X + (size_t)(r0 + r) * NHn + c4 * 4);
        *reinterpret_cast<float4*>(&hs[r][NHn + EHn + c4 * 4]) = f4relu(x4);
    }
    __syncthreads();                      // sync1

    const int t8 = tid & 255;
    const int rg = t8 >> 6;               // 0..3 (wave-uniform)
    const int c4 = t8 & 63;
    const int kh = tid >> 8;              // 0/1 (wave-uniform)
    const int ra = 2 * rg, rb = ra + 1;

    // ---- CS partials (64 threads) ----
    if (tid < 64) {
        const int r = tid >> 3, seg = tid & 7;
        float s = 0.f;
        #pragma unroll
        for (int i = 0; i < 16; ++i) s += asl[seg * 16 + i][r];
        pcs[r][seg] = s;
    }

    // ---- AX GEMM: AX[8][256] = asl^T @ X[b], K=128 (split 64/64) ----
    {
        const float* wb = X + (size_t)(b * Mn) * NHn + c4 * 4;  // "weights" = X rows
        const int k0 = kh * 64;
        float4 B0[4], B1[4];
        float4 a0 = f4zero(), a1 = f4zero();
        LOADW(B0, wb, NHn, k0);
        for (int k = k0; k < k0 + 64; k += 8) {
            LOADW(B1, wb, NHn, k + 4);
            {
                const float4 _b = B0[0];  // operands: asl[k..k+3][ra/rb]
                (void)_b;
            }
            {
                // 2-row FMA with per-k scalar operands from asl
                f4fma(a0, asl[k    ][ra], B0[0]); f4fma(a1, asl[k    ][rb], B0[0]);
                f4fma(a0, asl[k + 1][ra], B0[1]); f4fma(a1, asl[k + 1][rb], B0[1]);
                f4fma(a0, asl[k + 2][ra], B0[2]); f4fma(a1, asl[k + 2][rb], B0[2]);
                f4fma(a0, asl[k + 3][ra], B0[3]); f4fma(a1, asl[k + 3][rb], B0[3]);
            }
            if (k + 8 < k0 + 64) LOADW(B0, wb, NHn, k + 8);
            {
                f4fma(a0, asl[k + 4][ra], B1[0]); f4fma(a1, asl[k + 4][rb], B1[0]);
                f4fma(a0, asl[k + 5][ra], B1[1]); f4fma(a1, asl[k + 5][rb], B1[1]);
                f4fma(a0, asl[k + 6][ra], B1[2]); f4fma(a1, asl[k + 6][rb], B1[2]);
                f4fma(a0, asl[k + 7][ra], B1[3]); f4fma(a1, asl[k + 7][rb], B1[3]);
            }
        }
        if (kh == 1) { comb[t8][0] = a0; comb[t8][1] = a1; }
        __syncthreads();                  // sync2
        if (kh == 0) {
            a0 = f4add(a0, comb[t8][0]);
            a1 = f4add(a1, comb[t8][1]);
            *reinterpret_cast<float4*>(&axs[ra][c4 * 4]) = a0;
            *reinterpret_cast<float4*>(&axs[rb][c4 * 4]) = a1;
        }
        if (tid < 8) {
            float s = 0.f;
            #pragma unroll
            for (int g = 0; g < 8; ++g) s += pcs[tid][g];
            csb[tid] = s;
        }
        __syncthreads();                  // sync3
    }

    // ---- edge GEMM (tid<256): hs[:,256:384) = relu(T@We + CS*be), K=128 ----
    if (tid < 256) {
        const int er = tid >> 5;          // 0..7
        const int ec = tid & 31;          // f4 col of 32
        const float* wb = We + ec * 4;
        const float* opA = ts[er];
        float4 B0[4], B1[4];
        float4 a0 = f4zero();
        LOADW(B0, wb, EHn, 0);
        for (int k = 0; k < EHn; k += 8) {
            LOADW(B1, wb, EHn, k + 4);
            FMA1R(B0, k, opA);
            if (k + 8 < EHn) LOADW(B0, wb, EHn, k + 8);
            FMA1R(B1, k + 4, opA);
        }
        const float4 be = ld4(Web + ec * 4);
        f4fma(a0, csb[er], be);
        *reinterpret_cast<float4*>(&hs[er][NHn + ec * 4]) = f4relu(a0);
    }

    // ---- node GEMM: hs[:,0:256) = relu(AX@Wv + CS*bv), K=256 (split) ----
    {
        const float* wb = Wv + c4 * 4;
        const float* opA = axs[ra];
        const float* opB = axs[rb];
        const int k0 = kh * 128;
        float4 B0[4], B1[4];
        float4 a0 = f4zero(), a1 = f4zero();
        LOADW(B0, wb, NHn, k0);
        for (int k = k0; k < k0 + 128; k += 8) {
            LOADW(B1, wb, NHn, k + 4);
            FMA2R(B0, k, opA, opB);
            if (k + 8 < k0 + 128) LOADW(B0, wb, NHn, k + 8);
            FMA2R(B1, k + 4, opA, opB);
        }
        if (kh == 1) { comb[t8][0] = a0; comb[t8][1] = a1; }
        __syncthreads();                  // sync4
        if (kh == 0) {
            a0 = f4add(a0, comb[t8][0]);
            a1 = f4add(a1, comb[t8][1]);
            const float4 bv = ld4(Wvb + c4 * 4);
            f4fma(a0, csb[ra], bv);
            f4fma(a1, csb[rb], bv);
            *reinterpret_cast<float4*>(&hs[ra][c4 * 4]) = f4relu(a0);
            *reinterpret_cast<float4*>(&hs[rb][c4 * 4]) = f4relu(a1);
        }
        __syncthreads();                  // sync5
    }

    // ---- layer 2: out = (h @ Wu + bu) * w, K=640 (split 320/320) ----
    {
        const float* wb = Wu + c4 * 4;
        const float* opA = hs[ra];
        const float* opB = hs[rb];
        const int k0 = kh * 320;
        float4 B0[4], B1[4];
        float4 a0 = f4zero(), a1 = f4zero();
        LOADW(B0, wb, NHn, k0);
        for (int k = k0; k < k0 + 320; k += 8) {
            LOADW(B1, wb, NHn, k + 4);
            FMA2R(B0, k, opA, opB);
            if (k + 8 < k0 + 320) LOADW(B0, wb, NHn, k + 8);
            FMA2R(B1, k + 4, opA, opB);
        }
        if (kh == 1) { comb[t8][0] = a0; comb[t8][1] = a1; }
        __syncthreads();                  // sync6
        if (kh == 0) {
            a0 = f4add(a0, comb[t8][0]);
            a1 = f4add(a1, comb[t8][1]);
            const float4 bu = ld4(Wub + c4 * 4);
            const float w0 = wrow[r0 + ra], w1 = wrow[r0 + rb];
            float4 o0, o1;
            o0.x = (a0.x + bu.x) * w0;  o0.y = (a0.y + bu.y) * w0;
            o0.z = (a0.z + bu.z) * w0;  o0.w = (a0.w + bu.w) * w0;
            o1.x = (a1.x + bu.x) * w1;  o1.y = (a1.y + bu.y) * w1;
            o1.z = (a1.z + bu.z) * w1;  o1.w = (a1.w + bu.w) * w1;
            *reinterpret_cast<float4*>(out + (size_t)(r0 + ra) * NHn + c4 * 4) = o0;
            *reinterpret_cast<float4*>(out + (size_t)(r0 + rb) * NHn + c4 * 4) = o1;
        }
    }
}

} // anonymous namespace

extern "C" void kernel_launch(void* const* d_in, const int* in_sizes, int n_in,
                              void* d_out, int out_size, void* d_ws, size_t ws_size,
                              hipStream_t stream) {
    const float* X   = (const float*)d_in[0];   // [16,128,256]
    const float* E   = (const float*)d_in[1];   // [16,128,128,128]
    const float* A   = (const float*)d_in[2];   // [16,128,128]
    const float* w   = (const float*)d_in[3];   // [16,128,1]
    const float* Wv  = (const float*)d_in[4];   // [256,256]
    const float* Wvb = (const float*)d_in[5];   // [256]
    const float* We  = (const float*)d_in[6];   // [128,128]
    const float* Web = (const float*)d_in[7];   // [128]
    const float* Wu  = (const float*)d_in[8];   // [640,256]
    const float* Wub = (const float*)d_in[9];   // [256]
    float* out = (float*)d_out;                 // [16,128,256]

    float* T = (float*)d_ws;                    // 2048*128 floats = 1 MB

    k_reduce<<<512, 256, 0, stream>>>(E, A, T);
    k_mix<<<256, 512, 0, stream>>>(T, A, X, Wv, Wvb, We, Web, Wu, Wub, w, out);
}

// Round 8
// 258.804 us; speedup vs baseline: 1.3326x; 1.0058x over previous
//
#include <hip/hip_runtime.h>

namespace {

constexpr int Bn   = 16;
constexpr int Mn   = 128;
constexpr int NHn  = 256;
constexpr int EHn  = 128;
constexpr int ROWS = Bn * Mn;           // 2048
constexpr int HW   = 2 * NHn + EHn;     // 640

__device__ __forceinline__ float4 ld4(const float* p) {
    return *reinterpret_cast<const float4*>(p);
}
__device__ __forceinline__ float4 f4relu(const float4& a) {
    return make_float4(fmaxf(a.x, 0.f), fmaxf(a.y, 0.f),
                       fmaxf(a.z, 0.f), fmaxf(a.w, 0.f));
}

// ---------------------------------------------------------------------------
// Kernel 1: T[b,j,f] = sum_i A[b,i,j] * E[b,i,j,f]   (pure E stream)
// Block = (b, j-tile of 4): per i reads E[b,i,j0:j0+4,:] = 2 KB CONTIGUOUS;
// each output cell owned by one thread -> no reduction.
// 512 blocks x 256 thr = 2 blocks/CU, 8 waves/CU.
// ---------------------------------------------------------------------------
__global__ __launch_bounds__(256) void k_reduce(
    const float* __restrict__ E, const float* __restrict__ A,
    float* __restrict__ T)
{
    const int bid = blockIdx.x;           // 512 = 16 b x 32 j-tiles
    const int b   = bid >> 5;
    const int j0  = (bid & 31) * 4;
    const int tid = threadIdx.x;

    __shared__ float acolT[4][Mn];        // A[b, :, j0+jj] transposed

    if (tid < Mn) {
        const float4 a4 = ld4(A + (size_t)b * Mn * Mn + (size_t)tid * Mn + j0);
        acolT[0][tid] = a4.x; acolT[1][tid] = a4.y;
        acolT[2][tid] = a4.z; acolT[3][tid] = a4.w;
    }
    __syncthreads();

    const int jj = tid >> 6;              // 0..3 (wave-uniform)
    const int f2 = tid & 63;              // float2 index into 128 floats
    const float* Eb = E + (size_t)b * Mn * Mn * EHn + (size_t)(j0 + jj) * EHn
                        + f2 * 2;
    const float* ac = acolT[jj];

    float2 acc = make_float2(0.f, 0.f);
    #pragma unroll 16
    for (int i = 0; i < Mn; ++i) {
        const float2 e2 = *reinterpret_cast<const float2*>(
            Eb + (size_t)i * (Mn * EHn));
        const float a = ac[i];            // LDS broadcast
        acc.x = fmaf(a, e2.x, acc.x);
        acc.y = fmaf(a, e2.y, acc.y);
    }

    const int row = b * Mn + j0 + jj;
    *reinterpret_cast<float2*>(T + (size_t)row * EHn + f2 * 2) = acc;
}

// ---------------------------------------------------------------------------
// Kernel 2 (fused, 512 blocks x 256 thr, 2 blocks/CU): per 4-row tile:
//   CS, AX computed in-kernel from the A-slice + L2-resident X;
//   h = [ relu(AX@Wv+CS*bv) | relu(T@We+CS*be) | relu(X) ]  in LDS
//   out = (h @ Wu + bu) * w
// Thread = output column c (scalar): per k ONE coalesced 4B weight load +
// 4 FMAs vs LDS broadcasts; unroll 16 -> 16 loads in flight/wave,
// 2 waves/SIMD. Design target: L2-BW-bound (~560 MB @ 34.5 TB/s ~ 16 us),
// not latency-bound.
// ---------------------------------------------------------------------------
__global__ __launch_bounds__(256) void k_mix(
    const float* __restrict__ T, const float* __restrict__ A,
    const float* __restrict__ X,
    const float* __restrict__ Wv, const float* __restrict__ Wvb,
    const float* __restrict__ We, const float* __restrict__ Web,
    const float* __restrict__ Wu, const float* __restrict__ Wub,
    const float* __restrict__ wrow, float* __restrict__ out)
{
    const int bid = blockIdx.x;           // matches k_reduce tiling
    const int b   = bid >> 5;
    const int j0  = (bid & 31) * 4;
    const int r0  = b * Mn + j0;          // 4 global rows r0..r0+3
    const int tid = threadIdx.x;

    __shared__ float acolT[4][Mn];        // 2 KB
    __shared__ float ts[4][EHn];          // 2 KB
    __shared__ float axs[4][NHn];         // 4 KB
    __shared__ float hs[4][HW];           // 10.2 KB
    __shared__ float pec[2][4][EHn];      // 4 KB (edge split-K partials)
    __shared__ float pcs[4][16];
    __shared__ float csb[4];

    // ---- stage A-slice (transposed) and T ----
    if (tid < Mn) {
        const float4 a4 = ld4(A + (size_t)b * Mn * Mn + (size_t)tid * Mn + j0);
        acolT[0][tid] = a4.x; acolT[1][tid] = a4.y;
        acolT[2][tid] = a4.z; acolT[3][tid] = a4.w;
    } else {
        const int t = tid - 128;
        const int r = t >> 5, c = t & 31;
        *reinterpret_cast<float4*>(&ts[r][c * 4]) =
            ld4(T + (size_t)(r0 + r) * EHn + c * 4);
    }
    // stage relu(X) -> hs[:, 384:640)
    {
        const int r = tid >> 6, c = tid & 63;
        const float4 x4 = ld4(X + (size_t)(r0 + r) * NHn + c * 4);
        *reinterpret_cast<float4*>(&hs[r][NHn + EHn + c * 4]) = f4relu(x4);
    }
    __syncthreads();                      // sync1

    // ---- CS: wave-0 partials + combine (wave-lockstep, no barrier needed) ----
    if (tid < 64) {
        const int r = tid >> 4, s = tid & 15;
        float acc = 0.f;
        #pragma unroll
        for (int i = 0; i < 8; ++i) acc += acolT[r][s * 8 + i];
        pcs[r][s] = acc;
    }
    if (tid < 4) {
        float acc = 0.f;
        #pragma unroll
        for (int s = 0; s < 16; ++s) acc += pcs[tid][s];
        csb[tid] = acc;
    }

    // ---- AX[4][256] = acolT @ X[b] (K=128), thread = col c ----
    {
        const float* Xb = X + (size_t)(b * Mn) * NHn + tid;   // + k*NHn
        float a0 = 0.f, a1 = 0.f, a2 = 0.f, a3 = 0.f;
        for (int k = 0; k < Mn; k += 16) {
            float xw[16];
            #pragma unroll
            for (int u = 0; u < 16; ++u) xw[u] = Xb[(size_t)(k + u) * NHn];
            #pragma unroll
            for (int u = 0; u < 16; ++u) {
                a0 = fmaf(acolT[0][k + u], xw[u], a0);
                a1 = fmaf(acolT[1][k + u], xw[u], a1);
                a2 = fmaf(acolT[2][k + u], xw[u], a2);
                a3 = fmaf(acolT[3][k + u], xw[u], a3);
            }
        }
        axs[0][tid] = a0; axs[1][tid] = a1;
        axs[2][tid] = a2; axs[3][tid] = a3;
    }
    __syncthreads();                      // sync2 (axs + csb visible)

    // ---- node GEMM: hs[:, 0:256) = relu(AX @ Wv + CS*bv), K=256 ----
    {
        const float* Wvc = Wv + tid;
        float n0 = 0.f, n1 = 0.f, n2 = 0.f, n3 = 0.f;
        for (int k = 0; k < NHn; k += 16) {
            float wv[16];
            #pragma unroll
            for (int u = 0; u < 16; ++u) wv[u] = Wvc[(size_t)(k + u) * NHn];
            #pragma unroll
            for (int u = 0; u < 16; ++u) {
                n0 = fmaf(axs[0][k + u], wv[u], n0);
                n1 = fmaf(axs[1][k + u], wv[u], n1);
                n2 = fmaf(axs[2][k + u], wv[u], n2);
                n3 = fmaf(axs[3][k + u], wv[u], n3);
            }
        }
        const float bv = Wvb[tid];
        hs[0][tid] = fmaxf(fmaf(csb[0], bv, n0), 0.f);
        hs[1][tid] = fmaxf(fmaf(csb[1], bv, n1), 0.f);
        hs[2][tid] = fmaxf(fmaf(csb[2], bv, n2), 0.f);
        hs[3][tid] = fmaxf(fmaf(csb[3], bv, n3), 0.f);
    }

    // ---- edge GEMM: split-K (kh = tid>>7), cols 0..127, K half = 64 ----
    {
        const int kh = tid >> 7;          // wave-uniform
        const int c  = tid & 127;
        const int k0 = kh * 64;
        const float* Wec = We + c;
        float e0 = 0.f, e1 = 0.f, e2 = 0.f, e3 = 0.f;
        for (int k = k0; k < k0 + 64; k += 16) {
            float we[16];
            #pragma unroll
            for (int u = 0; u < 16; ++u) we[u] = Wec[(size_t)(k + u) * EHn];
            #pragma unroll
            for (int u = 0; u < 16; ++u) {
                e0 = fmaf(ts[0][k + u], we[u], e0);
                e1 = fmaf(ts[1][k + u], we[u], e1);
                e2 = fmaf(ts[2][k + u], we[u], e2);
                e3 = fmaf(ts[3][k + u], we[u], e3);
            }
        }
        pec[kh][0][c] = e0; pec[kh][1][c] = e1;
        pec[kh][2][c] = e2; pec[kh][3][c] = e3;
    }
    __syncthreads();                      // sync3
    if (tid < 128) {
        const float be = Web[tid];
        #pragma unroll
        for (int r = 0; r < 4; ++r) {
            const float e = pec[0][r][tid] + pec[1][r][tid];
            hs[r][NHn + tid] = fmaxf(fmaf(csb[r], be, e), 0.f);
        }
    }
    __syncthreads();                      // sync4 (hs complete)

    // ---- layer 2: out = (h @ Wu + bu) * w, K=640, thread = col c ----
    {
        const float* Wuc = Wu + tid;
        float o0 = 0.f, o1 = 0.f, o2 = 0.f, o3 = 0.f;
        for (int k = 0; k < HW; k += 16) {
            float wu[16];
            #pragma unroll
            for (int u = 0; u < 16; ++u) wu[u] = Wuc[(size_t)(k + u) * NHn];
            #pragma unroll
            for (int u = 0; u < 16; ++u) {
                o0 = fmaf(hs[0][k + u], wu[u], o0);
                o1 = fmaf(hs[1][k + u], wu[u], o1);
                o2 = fmaf(hs[2][k + u], wu[u], o2);
                o3 = fmaf(hs[3][k + u], wu[u], o3);
            }
        }
        const float bu = Wub[tid];
        out[(size_t)(r0 + 0) * NHn + tid] = (o0 + bu) * wrow[r0 + 0];
        out[(size_t)(r0 + 1) * NHn + tid] = (o1 + bu) * wrow[r0 + 1];
        out[(size_t)(r0 + 2) * NHn + tid] = (o2 + bu) * wrow[r0 + 2];
        out[(size_t)(r0 + 3) * NHn + tid] = (o3 + bu) * wrow[r0 + 3];
    }
}

} // anonymous namespace

extern "C" void kernel_launch(void* const* d_in, const int* in_sizes, int n_in,
                              void* d_out, int out_size, void* d_ws, size_t ws_size,
                              hipStream_t stream) {
    const float* X   = (const float*)d_in[0];   // [16,128,256]
    const float* E   = (const float*)d_in[1];   // [16,128,128,128]
    const float* A   = (const float*)d_in[2];   // [16,128,128]
    const float* w   = (const float*)d_in[3];   // [16,128,1]
    const float* Wv  = (const float*)d_in[4];   // [256,256]
    const float* Wvb = (const float*)d_in[5];   // [256]
    const float* We  = (const float*)d_in[6];   // [128,128]
    const float* Web = (const float*)d_in[7];   // [128]
    const float* Wu  = (const float*)d_in[8];   // [640,256]
    const float* Wub = (const float*)d_in[9];   // [256]
    float* out = (float*)d_out;                 // [16,128,256]

    float* T = (float*)d_ws;                    // 2048*128 floats = 1 MB

    k_reduce<<<512, 256, 0, stream>>>(E, A, T);
    k_mix<<<512, 256, 0, stream>>>(T, A, X, Wv, Wvb, We, Web, Wu, Wub, w, out);
}

// Round 9
// 253.891 us; speedup vs baseline: 1.3584x; 1.0194x over previous
//
#include <hip/hip_runtime.h>

namespace {

constexpr int Bn   = 16;
constexpr int Mn   = 128;
constexpr int NHn  = 256;
constexpr int EHn  = 128;
constexpr int HW   = 2 * NHn + EHn;     // 640

__device__ __forceinline__ float4 ld4(const float* p) {
    return *reinterpret_cast<const float4*>(p);
}
__device__ __forceinline__ void f4fma(float4& acc, float a, const float4& v) {
    acc.x = fmaf(a, v.x, acc.x);
    acc.y = fmaf(a, v.y, acc.y);
    acc.z = fmaf(a, v.z, acc.z);
    acc.w = fmaf(a, v.w, acc.w);
}
__device__ __forceinline__ float4 f4relu(const float4& a) {
    return make_float4(fmaxf(a.x, 0.f), fmaxf(a.y, 0.f),
                       fmaxf(a.z, 0.f), fmaxf(a.w, 0.f));
}

// ---------------------------------------------------------------------------
// Single fused kernel. Block = (b, j-tile of 4), 512 blocks x 256 thr
// (2 blocks/CU, 8 waves/CU). Phases (sequential per block):
//  1. stage A-columns (acolT), relu(X) -> hs tail;  CS from acolT
//  2. E-stream: T[4][128] = sum_i A*E  -> LDS (float4/lane, 1 KB/wave-instr,
//     2 KB contiguous per i; i split over 2 halves, combined via pt)
//     + AX[4][256] = acolT @ X  (scalar-column, X L2-resident)
//  3. node GEMM  hs[:,0:256)  = relu(AX@Wv + CS*bv)
//  4. edge GEMM  hs[:,256:384)= relu(T@We + CS*be)   (split-K over 2 halves)
//  5. layer 2    out = (hs @ Wu + bu) * w
// No workspace at all; T never leaves the CU.
// ---------------------------------------------------------------------------
__global__ __launch_bounds__(256) void k_fused(
    const float* __restrict__ E, const float* __restrict__ A,
    const float* __restrict__ X,
    const float* __restrict__ Wv, const float* __restrict__ Wvb,
    const float* __restrict__ We, const float* __restrict__ Web,
    const float* __restrict__ Wu, const float* __restrict__ Wub,
    const float* __restrict__ wrow, float* __restrict__ out)
{
    const int bid = blockIdx.x;           // 512 = 16 b x 32 j-tiles
    const int b   = bid >> 5;
    const int j0  = (bid & 31) * 4;
    const int r0  = b * Mn + j0;          // global rows r0..r0+3
    const int tid = threadIdx.x;

    __shared__ float  acolT[4][Mn];       // 2 KB   A[b,:,j0+jj]
    __shared__ float4 pt[2][4][32];       // 4 KB   E-phase partials
    __shared__ float  ts[4][EHn];         // 2 KB   T rows
    __shared__ float  axs[4][NHn];        // 4 KB   AX rows
    __shared__ float  hs[4][HW];          // 10.2 KB h rows
    __shared__ float  pec[2][4][EHn];     // 4 KB   edge split-K partials
    __shared__ float  pcs[4][16];
    __shared__ float  csb[4];

    // ---- phase 1: stage acolT + relu(X) ----
    if (tid < Mn) {
        const float4 a4 = ld4(A + (size_t)b * Mn * Mn + (size_t)tid * Mn + j0);
        acolT[0][tid] = a4.x; acolT[1][tid] = a4.y;
        acolT[2][tid] = a4.z; acolT[3][tid] = a4.w;
    }
    {
        const int r = tid >> 6, c = tid & 63;
        const float4 x4 = ld4(X + (size_t)(r0 + r) * NHn + c * 4);
        *reinterpret_cast<float4*>(&hs[r][NHn + EHn + c * 4]) = f4relu(x4);
    }
    __syncthreads();                      // sync1

    // ---- CS (wave 0, lockstep) ----
    if (tid < 64) {
        const int r = tid >> 4, s = tid & 15;
        float acc = 0.f;
        #pragma unroll
        for (int i = 0; i < 8; ++i) acc += acolT[r][s * 8 + i];
        pcs[r][s] = acc;
    }
    if (tid < 4) {
        float acc = 0.f;
        #pragma unroll
        for (int s = 0; s < 16; ++s) acc += pcs[tid][s];
        csb[tid] = acc;
    }

    // ---- phase 2a: E-stream -> pt ----
    {
        const int ih = tid >> 7;          // 0..1 (i parity)
        const int jj = (tid >> 5) & 3;    // 0..3
        const int f4 = tid & 31;          // float4 col
        const float* Eb = E + (size_t)b * Mn * Mn * EHn
                            + (size_t)ih * (Mn * EHn)
                            + (size_t)(j0 + jj) * EHn + f4 * 4;
        const float* ac = acolT[jj];
        float4 acc = make_float4(0.f, 0.f, 0.f, 0.f);
        #pragma unroll 8
        for (int it = 0; it < 64; ++it) {
            const float a  = ac[2 * it + ih];
            const float4 e4 = ld4(Eb + (size_t)it * (2 * Mn * EHn));
            f4fma(acc, a, e4);
        }
        pt[ih][jj][f4] = acc;
    }

    // ---- phase 2b: AX[4][256] = acolT @ X[b] (K=128), thread = col ----
    {
        const float* Xb = X + (size_t)(b * Mn) * NHn + tid;
        float a0 = 0.f, a1 = 0.f, a2 = 0.f, a3 = 0.f;
        for (int k = 0; k < Mn; k += 16) {
            float xw[16];
            #pragma unroll
            for (int u = 0; u < 16; ++u) xw[u] = Xb[(size_t)(k + u) * NHn];
            #pragma unroll
            for (int u = 0; u < 16; ++u) {
                a0 = fmaf(acolT[0][k + u], xw[u], a0);
                a1 = fmaf(acolT[1][k + u], xw[u], a1);
                a2 = fmaf(acolT[2][k + u], xw[u], a2);
                a3 = fmaf(acolT[3][k + u], xw[u], a3);
            }
        }
        axs[0][tid] = a0; axs[1][tid] = a1;
        axs[2][tid] = a2; axs[3][tid] = a3;
    }
    __syncthreads();                      // sync2 (pt, axs, csb visible)

    // ---- combine T halves (tid<128) ----
    if (tid < 128) {
        const int jj = tid >> 5, f4 = tid & 31;
        const float4 p0 = pt[0][jj][f4], p1 = pt[1][jj][f4];
        *reinterpret_cast<float4*>(&ts[jj][f4 * 4]) =
            make_float4(p0.x + p1.x, p0.y + p1.y, p0.z + p1.z, p0.w + p1.w);
    }

    // ---- phase 3: node GEMM hs[:,0:256) = relu(AX@Wv + CS*bv), K=256 ----
    {
        const float* Wvc = Wv + tid;
        float n0 = 0.f, n1 = 0.f, n2 = 0.f, n3 = 0.f;
        for (int k = 0; k < NHn; k += 16) {
            float wv[16];
            #pragma unroll
            for (int u = 0; u < 16; ++u) wv[u] = Wvc[(size_t)(k + u) * NHn];
            #pragma unroll
            for (int u = 0; u < 16; ++u) {
                n0 = fmaf(axs[0][k + u], wv[u], n0);
                n1 = fmaf(axs[1][k + u], wv[u], n1);
                n2 = fmaf(axs[2][k + u], wv[u], n2);
                n3 = fmaf(axs[3][k + u], wv[u], n3);
            }
        }
        const float bv = Wvb[tid];
        hs[0][tid] = fmaxf(fmaf(csb[0], bv, n0), 0.f);
        hs[1][tid] = fmaxf(fmaf(csb[1], bv, n1), 0.f);
        hs[2][tid] = fmaxf(fmaf(csb[2], bv, n2), 0.f);
        hs[3][tid] = fmaxf(fmaf(csb[3], bv, n3), 0.f);
    }
    __syncthreads();                      // sync3 (ts visible)

    // ---- phase 4: edge GEMM, split-K (kh = tid>>7), K half = 64 ----
    {
        const int kh = tid >> 7;
        const int c  = tid & 127;
        const int k0 = kh * 64;
        const float* Wec = We + c;
        float e0 = 0.f, e1 = 0.f, e2 = 0.f, e3 = 0.f;
        for (int k = k0; k < k0 + 64; k += 16) {
            float we[16];
            #pragma unroll
            for (int u = 0; u < 16; ++u) we[u] = Wec[(size_t)(k + u) * EHn];
            #pragma unroll
            for (int u = 0; u < 16; ++u) {
                e0 = fmaf(ts[0][k + u], we[u], e0);
                e1 = fmaf(ts[1][k + u], we[u], e1);
                e2 = fmaf(ts[2][k + u], we[u], e2);
                e3 = fmaf(ts[3][k + u], we[u], e3);
            }
        }
        pec[kh][0][c] = e0; pec[kh][1][c] = e1;
        pec[kh][2][c] = e2; pec[kh][3][c] = e3;
    }
    __syncthreads();                      // sync4
    if (tid < 128) {
        const float be = Web[tid];
        #pragma unroll
        for (int r = 0; r < 4; ++r) {
            const float e = pec[0][r][tid] + pec[1][r][tid];
            hs[r][NHn + tid] = fmaxf(fmaf(csb[r], be, e), 0.f);
        }
    }
    __syncthreads();                      // sync5 (hs complete)

    // ---- phase 5: layer 2, out = (h @ Wu + bu) * w, K=640 ----
    {
        const float* Wuc = Wu + tid;
        float o0 = 0.f, o1 = 0.f, o2 = 0.f, o3 = 0.f;
        for (int k = 0; k < HW; k += 16) {
            float wu[16];
            #pragma unroll
            for (int u = 0; u < 16; ++u) wu[u] = Wuc[(size_t)(k + u) * NHn];
            #pragma unroll
            for (int u = 0; u < 16; ++u) {
                o0 = fmaf(hs[0][k + u], wu[u], o0);
                o1 = fmaf(hs[1][k + u], wu[u], o1);
                o2 = fmaf(hs[2][k + u], wu[u], o2);
                o3 = fmaf(hs[3][k + u], wu[u], o3);
            }
        }
        const float bu = Wub[tid];
        out[(size_t)(r0 + 0) * NHn + tid] = (o0 + bu) * wrow[r0 + 0];
        out[(size_t)(r0 + 1) * NHn + tid] = (o1 + bu) * wrow[r0 + 1];
        out[(size_t)(r0 + 2) * NHn + tid] = (o2 + bu) * wrow[r0 + 2];
        out[(size_t)(r0 + 3) * NHn + tid] = (o3 + bu) * wrow[r0 + 3];
    }
}

} // anonymous namespace

extern "C" void kernel_launch(void* const* d_in, const int* in_sizes, int n_in,
                              void* d_out, int out_size, void* d_ws, size_t ws_size,
                              hipStream_t stream) {
    const float* X   = (const float*)d_in[0];   // [16,128,256]
    const float* E   = (const float*)d_in[1];   // [16,128,128,128]
    const float* A   = (const float*)d_in[2];   // [16,128,128]
    const float* w   = (const float*)d_in[3];   // [16,128,1]
    const float* Wv  = (const float*)d_in[4];   // [256,256]
    const float* Wvb = (const float*)d_in[5];   // [256]
    const float* We  = (const float*)d_in[6];   // [128,128]
    const float* Web = (const float*)d_in[7];   // [128]
    const float* Wu  = (const float*)d_in[8];   // [640,256]
    const float* Wub = (const float*)d_in[9];   // [256]
    float* out = (float*)d_out;                 // [16,128,256]

    k_fused<<<512, 256, 0, stream>>>(E, A, X, Wv, Wvb, We, Web, Wu, Wub, w, out);
}